// Round 2
// baseline (9319.150 us; speedup 1.0000x reference)
//
#include <hip/hip_runtime.h>
#include <hip/hip_bf16.h>
#include <hip/hip_cooperative_groups.h>

namespace cg = cooperative_groups;

#define TB 4096   // T*B
#define NB 32     // B
#define NT 128    // T
#define H 256

// ---------------------------------------------------------------------------
// K1: conv1(8x8 s4) + relu + conv2(4x4 s2) + relu, fused per (img) block.
// x: [4096][4][84][84], out y2: [4096][2592] (channel-major flatten, matches
// reshape(N,-1) of [N,32,9,9]).
// LDS: WBUF (W1 then W2, 32KB) + S1 (16x20x20, 25.6KB) < 64KB.
// ---------------------------------------------------------------------------
__global__ __launch_bounds__(256) void conv_front(
    const float* __restrict__ x,
    const float* __restrict__ w1, const float* __restrict__ b1,
    const float* __restrict__ w2, const float* __restrict__ b2,
    float* __restrict__ y2)
{
    __shared__ float WBUF[8192];          // W1 uses 4096, then W2 uses 8192
    __shared__ float S1[6400];            // conv1 out [16][20][20]
    __shared__ float B1s[16], B2s[32];

    const int img = blockIdx.x;
    const int tid = threadIdx.x;

    for (int f = tid; f < 4096; f += 256) WBUF[f] = w1[f];
    if (tid < 16) B1s[tid] = b1[tid];
    if (tid < 32) B2s[tid] = b2[tid];
    __syncthreads();

    const float* xi = x + (size_t)img * 4 * 84 * 84;

    // conv1: thread handles one spatial position (all 16 out-channels in regs)
    for (int pos = tid; pos < 400; pos += 256) {
        const int oy = pos / 20, ox = pos % 20;
        const int iy = oy * 4, ix = ox * 4;
        float acc[16];
        #pragma unroll
        for (int c = 0; c < 16; c++) acc[c] = B1s[c];
        for (int ci = 0; ci < 4; ci++) {
            #pragma unroll
            for (int ky = 0; ky < 8; ky++) {
                const float* xr = xi + ci * 7056 + (iy + ky) * 84 + ix; // 16B aligned
                const float4 x0 = *(const float4*)(xr);
                const float4 x1 = *(const float4*)(xr + 4);
                #pragma unroll
                for (int co = 0; co < 16; co++) {
                    const float* wr = &WBUF[((co * 4 + ci) * 8 + ky) * 8];
                    const float4 wa = *(const float4*)(wr);
                    const float4 wb = *(const float4*)(wr + 4);
                    acc[co] += x0.x * wa.x + x0.y * wa.y + x0.z * wa.z + x0.w * wa.w
                             + x1.x * wb.x + x1.y * wb.y + x1.z * wb.z + x1.w * wb.w;
                }
            }
        }
        #pragma unroll
        for (int co = 0; co < 16; co++)
            S1[co * 400 + pos] = fmaxf(acc[co], 0.f);
    }
    __syncthreads();

    for (int f = tid; f < 8192; f += 256) WBUF[f] = w2[f];
    __syncthreads();

    // conv2: 243 threads = 3 co-groups x 81 positions
    if (tid < 243) {
        const int cgI = tid / 81, pos = tid % 81;
        const int co0 = cgI * 11;
        const int ncg = (cgI == 2) ? 10 : 11;
        const int oy = pos / 9, ox = pos % 9;
        const int iy = oy * 2, ix = ox * 2;
        float acc[11];
        #pragma unroll
        for (int c = 0; c < 11; c++) acc[c] = (c < ncg) ? B2s[co0 + c] : 0.f;
        for (int ci = 0; ci < 16; ci++) {
            #pragma unroll
            for (int ky = 0; ky < 4; ky++) {
                const float* sr = &S1[ci * 400 + (iy + ky) * 20 + ix]; // 8B aligned
                const float2 f0 = *(const float2*)(sr);
                const float2 f1 = *(const float2*)(sr + 2);
                for (int c = 0; c < ncg; c++) {
                    const float4 w4 = *(const float4*)&WBUF[((co0 + c) * 16 + ci) * 16 + ky * 4];
                    acc[c] += f0.x * w4.x + f0.y * w4.y + f1.x * w4.z + f1.y * w4.w;
                }
            }
        }
        float* yo = y2 + (size_t)img * 2592;
        for (int c = 0; c < ncg; c++)
            yo[(co0 + c) * 81 + pos] = fmaxf(acc[c], 0.f);
    }
}

// ---------------------------------------------------------------------------
// Generic GEMM: C[M,N] = act(A[M,K] @ W[N,K]^T + bias), W row-major [N][K].
// Block: 256 threads -> tile [32 m x 256 n]; thread j holds acc[32] (one col).
// ---------------------------------------------------------------------------
__global__ __launch_bounds__(256) void gemm_bt(
    const float* __restrict__ A, const float* __restrict__ W,
    const float* __restrict__ bias, float* __restrict__ C,
    int M, int N, int K, int do_relu)
{
    __shared__ float Asub[32][36];
    __shared__ float Wsub[256][36];

    const int m0 = blockIdx.x * 32;
    const int n0 = blockIdx.y * 256;
    const int tid = threadIdx.x;
    const int j = n0 + tid;

    float acc[32];
    #pragma unroll
    for (int i = 0; i < 32; i++) acc[i] = 0.f;

    for (int k0 = 0; k0 < K; k0 += 32) {
        #pragma unroll
        for (int r = 0; r < 4; r++) {
            int f = tid + 256 * r, mi = f >> 5, kk = f & 31;
            float v = 0.f;
            if (k0 + kk < K) v = A[(size_t)(m0 + mi) * K + k0 + kk];
            Asub[mi][kk] = v;
        }
        #pragma unroll
        for (int r = 0; r < 32; r++) {
            int f = tid + 256 * r, ni = f >> 5, kk = f & 31;
            float v = 0.f;
            if (n0 + ni < N && k0 + kk < K) v = W[(size_t)(n0 + ni) * K + k0 + kk];
            Wsub[ni][kk] = v;
        }
        __syncthreads();
        #pragma unroll
        for (int kk = 0; kk < 32; kk += 4) {
            const float4 w4 = *(const float4*)&Wsub[tid][kk];
            #pragma unroll
            for (int i = 0; i < 32; i++) {
                const float4 a4 = *(const float4*)&Asub[i][kk];
                acc[i] += a4.x * w4.x + a4.y * w4.y + a4.z * w4.z + a4.w * w4.w;
            }
        }
        __syncthreads();
    }

    if (j < N) {
        const float bv = bias[j];
        #pragma unroll
        for (int i = 0; i < 32; i++) {
            float v = acc[i] + bv;
            if (do_relu) v = fmaxf(v, 0.f);
            C[(size_t)(m0 + i) * N + j] = v;
        }
    }
}

// ---------------------------------------------------------------------------
// K3: GRU scan (cooperative). 64 blocks = 2 nets x 32 h-slices (8 idx each).
// Ping-pong hbuf: step t reads hbuf[t&1], writes hbuf[(t+1)&1] -> one
// grid.sync per step, no read/write race across blocks.
// ---------------------------------------------------------------------------
__global__ __launch_bounds__(256) void gru_scan(
    const float* __restrict__ gi,     // [2][4096][768] (bih already added)
    const float* __restrict__ whh_a, const float* __restrict__ whh_c,
    const float* __restrict__ bhh_a, const float* __restrict__ bhh_c,
    const float* __restrict__ done,   // [4096]
    float* __restrict__ hbuf,         // [2 pingpong][2 net][32][256]
    float* __restrict__ hid)          // [2][4096][256] relu(h_t)
{
    cg::grid_group gg = cg::this_grid();
    const int bid = blockIdx.x;
    const int net = bid >> 5;
    const int jb  = bid & 31;
    const int i0  = jb * 8;
    const float* whh = net ? whh_c : whh_a;
    const float* bhh = net ? bhh_c : bhh_a;
    const int tid = threadIdx.x;
    const int b  = tid & 31;
    const int il = tid >> 5;
    const int ig = i0 + il;

    __shared__ float Wl[24][260];   // [gate*8 + il][k]
    __shared__ float Hl[32][260];   // masked h, [b][k]

    for (int f = tid; f < 24 * 256; f += 256) {
        const int row = f >> 8, k = f & 255;
        const int g = row / 8, ilr = row % 8;
        Wl[row][k] = whh[(size_t)(g * 256 + i0 + ilr) * 256 + k];
    }
    const float bh_r = bhh[ig], bh_z = bhh[256 + ig], bh_n = bhh[512 + ig];
    __syncthreads();

    for (int t = 0; t < NT; t++) {
        const float* hsrc = hbuf + (size_t)(t & 1) * 16384 + net * 8192;
        float*       hdst = hbuf + (size_t)((t + 1) & 1) * 16384 + net * 8192;

        #pragma unroll
        for (int r = 0; r < 32; r++) {
            const float hv = hsrc[r * 256 + tid];
            const float d = done[t * 32 + r];
            Hl[r][tid] = (1.f - d) * hv;
        }
        __syncthreads();

        float ar = 0.f, az = 0.f, an = 0.f;
        const float* wr = &Wl[il][0];
        const float* wz = &Wl[8 + il][0];
        const float* wn = &Wl[16 + il][0];
        const float* hb = &Hl[b][0];
        #pragma unroll 4
        for (int k = 0; k < 256; k += 4) {
            const float4 hv = *(const float4*)(hb + k);
            const float4 w1 = *(const float4*)(wr + k);
            const float4 w2 = *(const float4*)(wz + k);
            const float4 w3 = *(const float4*)(wn + k);
            ar += hv.x * w1.x + hv.y * w1.y + hv.z * w1.z + hv.w * w1.w;
            az += hv.x * w2.x + hv.y * w2.y + hv.z * w2.z + hv.w * w2.w;
            an += hv.x * w3.x + hv.y * w3.y + hv.z * w3.z + hv.w * w3.w;
        }

        const float* gp = gi + ((size_t)net * TB + t * 32 + b) * 768 + ig;
        const float gir = gp[0], giz = gp[256], gin = gp[512];
        const float rr = 1.f / (1.f + expf(-(gir + ar + bh_r)));
        const float zz = 1.f / (1.f + expf(-(giz + az + bh_z)));
        const float nn = tanhf(gin + rr * (an + bh_n));
        const float hm = Hl[b][ig];
        const float hnew = (1.f - zz) * nn + zz * hm;

        hdst[b * 256 + ig] = hnew;
        hid[((size_t)net * TB + t * 32 + b) * 256 + ig] = fmaxf(hnew, 0.f);

        __threadfence();
        gg.sync();
    }
}

// ---------------------------------------------------------------------------
// K5: heads — actor logits/log_softmax/logp/entropy + critic value (f32 out).
// ---------------------------------------------------------------------------
__global__ __launch_bounds__(256) void heads(
    const float* __restrict__ m2a, const float* __restrict__ m2c,
    const float* __restrict__ aw3, const float* __restrict__ ab3,
    const float* __restrict__ cw3, const float* __restrict__ cb3,
    const int* __restrict__ action,
    float* __restrict__ out)
{
    __shared__ float AW[700], AB[7], CW[100], CB1;
    const int tid = threadIdx.x;
    for (int f = tid; f < 700; f += 256) AW[f] = aw3[f];
    if (tid < 7)   AB[tid] = ab3[tid];
    if (tid < 100) CW[tid] = cw3[tid];
    if (tid == 0)  CB1 = cb3[0];
    __syncthreads();

    const int r = blockIdx.x * 256 + tid;
    if (r >= TB) return;

    const float* m = m2a + (size_t)r * 100;
    float l[7];
    #pragma unroll
    for (int jj = 0; jj < 7; jj++) {
        float s = AB[jj];
        for (int k = 0; k < 100; k++) s += m[k] * AW[jj * 100 + k];
        l[jj] = s;
    }
    float mx = l[0];
    #pragma unroll
    for (int jj = 1; jj < 7; jj++) mx = fmaxf(mx, l[jj]);
    float se = 0.f;
    #pragma unroll
    for (int jj = 0; jj < 7; jj++) se += expf(l[jj] - mx);
    const float lse = logf(se);
    const int a = action[r];
    float ent = 0.f, lp_a = 0.f;
    #pragma unroll
    for (int jj = 0; jj < 7; jj++) {
        const float lp = l[jj] - mx - lse;
        ent -= expf(lp) * lp;
        if (jj == a) lp_a = lp;
    }

    const float* mc = m2c + (size_t)r * 100;
    float v = CB1;
    for (int k = 0; k < 100; k++) v += mc[k] * CW[k];

    out[r]            = (float)a;
    out[TB + r]       = lp_a;
    out[2 * TB + r]   = ent;
    out[3 * TB + r]   = v;
}

// ---------------------------------------------------------------------------
extern "C" void kernel_launch(void* const* d_in, const int* in_sizes, int n_in,
                              void* d_out, int out_size, void* d_ws, size_t ws_size,
                              hipStream_t stream)
{
    const float* x     = (const float*)d_in[0];
    const float* gru0  = (const float*)d_in[1];
    const float* done  = (const float*)d_in[2];
    const int*   act   = (const int*)d_in[3];
    #define AIN(i) ((const float*)d_in[4 + (i)])
    #define CIN(i) ((const float*)d_in[20 + (i)])
    // per-net order: c1w,c1b,c2w,c2b,fw,fb,wih,whh,bih,bhh,h1w,h1b,h2w,h2b,h3w,h3b

    // Workspace aliasing (peak ~50.9 MB):
    // region1 (10,616,832 f): y2 during conv/FC phase; then gi+m1+m2+hbuf.
    // region2 (2,097,152 f):  feats during FC/gi phase; then hid.
    float* ws = (float*)d_ws;
    float* region1 = ws;
    float* region2 = ws + (size_t)TB * 2592;

    float* y2    = region1;                        // [4096][2592]
    float* gi    = region1;                        // [2][4096][768] (after y2 dead)
    float* m1    = gi + (size_t)2 * TB * 768;      // [2][4096][200]
    float* m2    = m1 + (size_t)2 * TB * 200;      // [2][4096][100]
    float* hbuf  = m2 + (size_t)2 * TB * 100;      // [2 pingpong][2][32][256]

    float* feats = region2;                        // [2][4096][256]
    float* hid   = region2;                        // [2][4096][256] (after feats dead)

    float* feats_c = feats + (size_t)TB * 256;
    float* gi_c    = gi    + (size_t)TB * 768;
    float* hid_c   = hid   + (size_t)TB * 256;
    float* m1_c    = m1    + (size_t)TB * 200;
    float* m2_c    = m2    + (size_t)TB * 100;

    // ---- actor CNN + FC ----
    conv_front<<<TB, 256, 0, stream>>>(x, AIN(0), AIN(1), AIN(2), AIN(3), y2);
    gemm_bt<<<dim3(TB / 32, 1), 256, 0, stream>>>(y2, AIN(4), AIN(5), feats,
                                                  TB, 256, 2592, 1);
    // ---- critic CNN + FC (reuse y2) ----
    conv_front<<<TB, 256, 0, stream>>>(x, CIN(0), CIN(1), CIN(2), CIN(3), y2);
    gemm_bt<<<dim3(TB / 32, 1), 256, 0, stream>>>(y2, CIN(4), CIN(5), feats_c,
                                                  TB, 256, 2592, 1);

    // ---- gi = feats @ wih^T + bih (both nets); y2 dead, gi aliases region1 ----
    gemm_bt<<<dim3(TB / 32, 3), 256, 0, stream>>>(feats, AIN(6), AIN(8), gi,
                                                  TB, 768, 256, 0);
    gemm_bt<<<dim3(TB / 32, 3), 256, 0, stream>>>(feats_c, CIN(6), CIN(8), gi_c,
                                                  TB, 768, 256, 0);

    // ---- init h (pingpong buf 0), cooperative scan ----
    hipMemcpyAsync(hbuf, gru0, (size_t)2 * NB * H * sizeof(float),
                   hipMemcpyDeviceToDevice, stream);
    {
        const float* gi_p = gi;
        const float* whh_a = AIN(7); const float* whh_c = CIN(7);
        const float* bhh_a = AIN(9); const float* bhh_c = CIN(9);
        const float* done_p = done;
        float* hbuf_p = hbuf; float* hid_p = hid;
        void* args[] = {(void*)&gi_p, (void*)&whh_a, (void*)&whh_c,
                        (void*)&bhh_a, (void*)&bhh_c, (void*)&done_p,
                        (void*)&hbuf_p, (void*)&hid_p};
        hipLaunchCooperativeKernel((void*)gru_scan, dim3(64), dim3(256),
                                   args, 0, stream);
    }

    // ---- MLPs ----
    gemm_bt<<<dim3(TB / 32, 1), 256, 0, stream>>>(hid, AIN(10), AIN(11), m1,
                                                  TB, 200, 256, 1);
    gemm_bt<<<dim3(TB / 32, 1), 256, 0, stream>>>(hid_c, CIN(10), CIN(11), m1_c,
                                                  TB, 200, 256, 1);
    gemm_bt<<<dim3(TB / 32, 1), 256, 0, stream>>>(m1, AIN(12), AIN(13), m2,
                                                  TB, 100, 200, 1);
    gemm_bt<<<dim3(TB / 32, 1), 256, 0, stream>>>(m1_c, CIN(12), CIN(13), m2_c,
                                                  TB, 100, 200, 1);

    // ---- heads + hT ----
    float* out = (float*)d_out;
    heads<<<TB / 256, 256, 0, stream>>>(m2, m2_c, AIN(14), AIN(15),
                                        CIN(14), CIN(15), act, out);
    // final h is in pingpong buf (NT&1)==0
    hipMemcpyAsync(out + 4 * TB, hbuf, (size_t)2 * NB * H * sizeof(float),
                   hipMemcpyDeviceToDevice, stream);
}